// Round 13
// baseline (287.326 us; speedup 1.0000x reference)
//
#include <hip/hip_runtime.h>
#include <hip/hip_bf16.h>

// Problem constants
#define NN    8
#define CC    32
#define HH    48
#define WW    48
#define OCC   32
#define HID   256
#define FEAT  288          // C*K*K
#define RTOT  9216         // (H*S)*(W*S)
#define COLS  9216         // FEAT*OC
#define XUP   96
#define YUP   96
#define OUTSZ (NN*OCC*XUP*YUP)   // 2,359,296 floats

using bf16x8 = __attribute__((ext_vector_type(8))) __bf16;
using bf16x4 = __attribute__((ext_vector_type(4))) __bf16;
using f32x4  = __attribute__((ext_vector_type(4))) float;
using f32x2  = __attribute__((ext_vector_type(2))) float;

// ---------------------------------------------------------------------------
// Kernel 1: hmid = relu(v @ w1 + b1), bf16, MFMA A-fragment order (verified):
//   frag = (r/16)*8 + k/32 ; lane = ((k/8)%4)*16 + r%16 ; elem = k%8
// ---------------------------------------------------------------------------
__global__ void prep_hmid(const float* __restrict__ v, const float* __restrict__ w1,
                          const float* __restrict__ b1, __hip_bfloat16* __restrict__ hmidp) {
  int r = blockIdx.x;      // 0..9215
  int t = threadIdx.x;     // 0..255 = hidden index k
  float v0 = v[r*3+0], v1 = v[r*3+1], v2 = v[r*3+2];
  float val = v0*w1[t] + v1*w1[HID+t] + v2*w1[2*HID+t] + b1[t];
  val = fmaxf(val, 0.0f);
  int dst = ((r>>4)*8 + (t>>5))*512 + ((t>>3)&3)*128 + (r&15)*8 + (t&7);
  hmidp[dst] = __float2bfloat16(val);
}

// ---------------------------------------------------------------------------
// Kernel 2: w2 -> bf16, B-fragment order grouped into 8KB slices (verified):
//   colchunk = col/128 (72), kb = k/32 (8), cg = (col%128)/16 (8),
//   lane = ((k/8)%4)*16 + col%16, elem = k%8
// ---------------------------------------------------------------------------
__global__ void prep_w2(const float* __restrict__ w2, __hip_bfloat16* __restrict__ w2p) {
  int idx = blockIdx.x*256 + threadIdx.x;   // 0 .. 256*9216-1
  int k   = idx / COLS;
  int col = idx % COLS;
  float val = w2[idx];                      // w2[k][col], row-major
  int colchunk = col >> 7;
  int cg   = (col >> 4) & 7;
  int lane = (((k>>3)&3)<<4) | (col & 15);
  int kb   = k >> 5;
  int i    = k & 7;
  int dst  = (((colchunk*8 + kb)*8 + cg)*64 + lane)*8 + i;
  w2p[dst] = __float2bfloat16(val);
}

// ---------------------------------------------------------------------------
// Kernel 3: fused GEMM + apply. = passing R11 core with three levers:
//   (1) G=4: 1152 blocks, XCD-pinned g (g = xcd&3), bijective chunked decode.
//   (2) LDS 48.6KB + launch_bounds(256,3): 3 blocks/CU resident -> 12 waves/CU
//       cross-wave hiding of the (compiler-sunk) B-load latency.
//   (3) f32x2 packed apply accumulators (v_pk_fma_f32): halves apply VALU.
// ---------------------------------------------------------------------------
#define BARRIER_LGKM() do {                              \
    asm volatile("s_waitcnt lgkmcnt(0)" ::: "memory");   \
    __builtin_amdgcn_sched_barrier(0);                   \
    __builtin_amdgcn_s_barrier();                        \
  } while (0)

#define ISSUE_HALF(SET, CH, H) do {                                              \
    const char* _b = w2base + ((size_t)((CH)*8 + (H)*4))*8192 + wv*2048          \
                     + (size_t)lane*16;                                          \
    _Pragma("unroll")                                                            \
    for (int _i = 0; _i < 4; ++_i) {                                             \
      SET[0][_i] = *(const bf16x8*)(_b + _i*8192);                               \
      SET[1][_i] = *(const bf16x8*)(_b + _i*8192 + 1024);                        \
    }                                                                            \
  } while (0)

__launch_bounds__(256, 3)
__global__ void fused_main(const float* __restrict__ F_LR,
                           const __hip_bfloat16* __restrict__ hmidp,
                           const __hip_bfloat16* __restrict__ w2p,
                           const float* __restrict__ b2,
                           float* __restrict__ outp,
                           int G, int nch) {
  extern __shared__ __align__(16) char smem[];
  __bf16* patB  = (__bf16*)smem;                 // 27648B: pat[c][ki][wi(18)][n(8)]
  float*  wc    = (float*)(smem + 27648);        // 16384B: [fl][oc][r^swz]
  __bf16* biasL = (__bf16*)(smem + 44032);       // nch*128 bf16

  const int tid  = threadIdx.x;
  const int lane = tid & 63;
  const int wv   = tid >> 6;
  const int blk  = blockIdx.x;
  int rowtile, g;
  if (G == 4) {            // 1152 blocks: xcd = blk&7 pinned to g = xcd&3
    int xcd = blk & 7;
    int j   = blk >> 3;    // 0..143
    g       = xcd & 3;
    rowtile = (xcd >> 2)*144 + j;
  } else if (G == 2) {     // 576 blocks: XCD-chunked (R10-proven)
    int xcd = blk & 7;
    int j   = blk >> 3;    // 0..71
    g       = xcd & 1;
    rowtile = (xcd >> 1)*72 + j;
  } else {
    rowtile = blk;
    g       = 0;
  }
  const int X  = rowtile / 3;
  const int Yh = rowtile - X*3;
  const int h  = X >> 1;
  const int w0 = Yh * 16;
  const int l15 = lane & 15;
  const int qt  = lane >> 4;
  const int oc  = lane & 31;
  const int nh  = lane >> 5;

  const char* w2base = (const char*)w2p + (size_t)g*nch*65536;

  // ---- A fragments -> registers (16 coalesced b128 loads) ----
  bf16x8 a[2][8];
  {
    const bf16x8* ap = reinterpret_cast<const bf16x8*>(hmidp) + (size_t)rowtile*1024 + lane;
    #pragma unroll
    for (int mg = 0; mg < 2; ++mg)
      #pragma unroll
      for (int kb = 0; kb < 8; ++kb) a[mg][kb] = ap[(mg*8 + kb)*64];
  }

  // ---- bias table -> LDS (bf16, one-time) ----
  for (int i = tid; i < nch*128; i += 256)
    biasL[i] = (__bf16)b2[g*nch*128 + i];

  // ---- stage patches: pat[c][ki][wi][n]; thread = (n,c) ----
  {
    const int n = tid >> 5, c = tid & 31;
    const float* fsrc = F_LR + ((size_t)(n*CC + c)*HH)*WW;
    #pragma unroll
    for (int ki = 0; ki < 3; ++ki) {
      int hh = h - 1 + ki;
      bool hok = (unsigned)hh < (unsigned)HH;
      #pragma unroll
      for (int wi = 0; wi < 18; ++wi) {
        int ww = w0 - 1 + wi;
        float val = (hok && (unsigned)ww < (unsigned)WW) ? fsrc[hh*WW + ww] : 0.f;
        patB[((c*3 + ki)*18 + wi)*8 + n] = (__bf16)val;
      }
    }
  }
  BARRIER_LGKM();

  f32x2 oacc2[8][2];                     // [row][q-pair] packed accumulators
  #pragma unroll
  for (int i = 0; i < 8; ++i) { oacc2[i][0] = 0.f; oacc2[i][1] = 0.f; }

  // ---- B double buffer: two half-chunk register sets ----
  bf16x8 bA[2][4], bB[2][4];
  ISSUE_HALF(bA, 0, 0);
  ISSUE_HALF(bB, 0, 1);

  for (int ch = 0; ch < nch; ++ch) {
    f32x4 acc00 = {0,0,0,0}, acc01 = {0,0,0,0}, acc10 = {0,0,0,0}, acc11 = {0,0,0,0};

    #pragma unroll
    for (int s = 0; s < 4; ++s) {
      acc00 = __builtin_amdgcn_mfma_f32_16x16x32_bf16(a[0][s], bA[0][s], acc00, 0,0,0);
      acc01 = __builtin_amdgcn_mfma_f32_16x16x32_bf16(a[0][s], bA[1][s], acc01, 0,0,0);
      acc10 = __builtin_amdgcn_mfma_f32_16x16x32_bf16(a[1][s], bA[0][s], acc10, 0,0,0);
      acc11 = __builtin_amdgcn_mfma_f32_16x16x32_bf16(a[1][s], bA[1][s], acc11, 0,0,0);
    }
    if (ch + 1 < nch) { ISSUE_HALF(bA, ch+1, 0); }

    #pragma unroll
    for (int s = 0; s < 4; ++s) {
      acc00 = __builtin_amdgcn_mfma_f32_16x16x32_bf16(a[0][4+s], bB[0][s], acc00, 0,0,0);
      acc01 = __builtin_amdgcn_mfma_f32_16x16x32_bf16(a[0][4+s], bB[1][s], acc01, 0,0,0);
      acc10 = __builtin_amdgcn_mfma_f32_16x16x32_bf16(a[1][4+s], bB[0][s], acc10, 0,0,0);
      acc11 = __builtin_amdgcn_mfma_f32_16x16x32_bf16(a[1][4+s], bB[1][s], acc11, 0,0,0);
    }
    if (ch + 1 < nch) { ISSUE_HALF(bB, ch+1, 1); }

    // ---- wc write: wc[fl(=wv)][oc][r^swz] = acc + bias ----
    {
      float bias0 = (float)biasL[ch*128 + wv*32 + l15];
      float bias1 = (float)biasL[ch*128 + wv*32 + 16 + l15];
      #pragma unroll
      for (int mg = 0; mg < 2; ++mg) {
        #pragma unroll
        for (int ng = 0; ng < 2; ++ng) {
          f32x4 A = (mg==0) ? (ng==0?acc00:acc01) : (ng==0?acc10:acc11);
          float bb = ng ? bias1 : bias0;
          A[0]+=bb; A[1]+=bb; A[2]+=bb; A[3]+=bb;
          int ocx  = ng*16 + l15;
          int ridx = (mg*16 + qt*4) ^ ((ocx&7)<<2);
          *(f32x4*)&wc[wv*1024 + ocx*32 + ridx] = A;
        }
      }
    }
    BARRIER_LGKM();                        // wc visible (vmem stays in flight)

    // ---- apply (packed f32x2 math) ----
    const int swz = (oc & 7) << 2;
    #pragma unroll
    for (int fl = 0; fl < 4; ++fl) {
      const int f   = (g*nch + ch)*4 + fl;
      const int c   = f / 9;
      const int rem = f - c*9;
      const int ki  = rem / 3;
      const int kj  = rem - ki*3;
      const f32x4 wlo = *(const f32x4*)&wc[fl*1024 + oc*32 + ((wv*8    ) ^ swz)];
      const f32x4 whi = *(const f32x4*)&wc[fl*1024 + oc*32 + ((wv*8 + 4) ^ swz)];
      const __bf16* pbase = patB + (c*3 + ki)*144 + nh*4;
      #pragma unroll
      for (int rrh = 0; rrh < 4; ++rrh) {
        bf16x4 pq = *(const bf16x4*)(pbase + (wv*4 + rrh + kj)*8);
        f32x2 p01; p01[0] = (float)pq[0]; p01[1] = (float)pq[1];
        f32x2 p23; p23[0] = (float)pq[2]; p23[1] = (float)pq[3];
        float w0v = (rrh < 2) ? ((rrh == 0) ? wlo[0] : wlo[2]) : ((rrh == 2) ? whi[0] : whi[2]);
        float w1v = (rrh < 2) ? ((rrh == 0) ? wlo[1] : wlo[3]) : ((rrh == 2) ? whi[1] : whi[3]);
        oacc2[rrh*2][0]   += p01 * w0v;
        oacc2[rrh*2][1]   += p23 * w0v;
        oacc2[rrh*2+1][0] += p01 * w1v;
        oacc2[rrh*2+1][1] += p23 * w1v;
      }
    }
    BARRIER_LGKM();                        // apply done; wc reusable
  }

  // ---- epilogue: out[n, oc, X, Yh*32 + wv*8 .. +7] ----
  float* OP = outp + (size_t)g*OUTSZ;
  #pragma unroll
  for (int q = 0; q < 4; ++q) {
    int n = nh*4 + q;
    f32x4 v0, v1;
    v0[0]=oacc2[0][q>>1][q&1]; v0[1]=oacc2[1][q>>1][q&1];
    v0[2]=oacc2[2][q>>1][q&1]; v0[3]=oacc2[3][q>>1][q&1];
    v1[0]=oacc2[4][q>>1][q&1]; v1[1]=oacc2[5][q>>1][q&1];
    v1[2]=oacc2[6][q>>1][q&1]; v1[3]=oacc2[7][q>>1][q&1];
    float* dst = OP + (((size_t)(n*OCC + oc)*XUP + X)*YUP + Yh*32 + wv*8);
    *(f32x4*)dst     = v0;
    *(f32x4*)(dst+4) = v1;
  }
}

// ---------------------------------------------------------------------------
// Kernel 4: out = sum of G partial buffers (deterministic)
// ---------------------------------------------------------------------------
__global__ void reduceG(const float* __restrict__ P, float* __restrict__ out, int G) {
  int i = blockIdx.x*256 + threadIdx.x;
  if (i < OUTSZ/4) {
    f32x4 s = ((const f32x4*)P)[i];
    for (int p = 1; p < G; ++p)
      s += ((const f32x4*)(P + (size_t)p*OUTSZ))[i];
    ((f32x4*)out)[i] = s;
  }
}

// ---------------------------------------------------------------------------
extern "C" void kernel_launch(void* const* d_in, const int* in_sizes, int n_in,
                              void* d_out, int out_size, void* d_ws, size_t ws_size,
                              hipStream_t stream) {
  const float* F_LR = (const float*)d_in[0];
  const float* v    = (const float*)d_in[1];
  const float* w1   = (const float*)d_in[2];
  const float* b1   = (const float*)d_in[3];
  const float* w2   = (const float*)d_in[4];
  const float* b2   = (const float*)d_in[5];
  float* out = (float*)d_out;

  const size_t prepBytes = (size_t)RTOT*HID*2;              // 4,718,592 each
  const size_t need4 = 2*prepBytes + 4ull*OUTSZ*4;          // 47,185,920
  const size_t need2 = 2*prepBytes + 2ull*OUTSZ*4;          // 28,311,552
  const int G   = (ws_size >= need4) ? 4 : (ws_size >= need2) ? 2 : 1;
  const int nch = 72 / G;

  __hip_bfloat16* hmidp = (__hip_bfloat16*)d_ws;
  __hip_bfloat16* w2p   = (__hip_bfloat16*)((char*)d_ws + prepBytes);
  float* P = (float*)((char*)d_ws + 2*prepBytes);
  float* target = (G > 1) ? P : out;

  const size_t shmem = 27648 + 16384 + (size_t)nch*128*2;   // 48,640 (G=4)

  hipLaunchKernelGGL(prep_hmid, dim3(RTOT), dim3(HID), 0, stream, v, w1, b1, hmidp);
  hipLaunchKernelGGL(prep_w2,   dim3((HID*COLS)/256), dim3(256), 0, stream, w2, w2p);
  hipLaunchKernelGGL(fused_main, dim3(288*G), dim3(256), shmem, stream,
                     F_LR, hmidp, w2p, b2, target, G, nch);
  if (G > 1)
    hipLaunchKernelGGL(reduceG, dim3(OUTSZ/4/256), dim3(256), 0, stream, P, out, G);
}

// Round 14
// 270.451 us; speedup vs baseline: 1.0624x; 1.0624x over previous
//
#include <hip/hip_runtime.h>
#include <hip/hip_bf16.h>

// Problem constants
#define NN    8
#define CC    32
#define HH    48
#define WW    48
#define OCC   32
#define HID   256
#define FEAT  288          // C*K*K
#define RTOT  9216         // (H*S)*(W*S)
#define COLS  9216         // FEAT*OC
#define XUP   96
#define YUP   96
#define OUTSZ (NN*OCC*XUP*YUP)   // 2,359,296 floats

using bf16x8 = __attribute__((ext_vector_type(8))) __bf16;
using f32x4  = __attribute__((ext_vector_type(4))) float;
using f32x2  = __attribute__((ext_vector_type(2))) float;

#define GLOAD_LDS16(gp, lp)                                                        \
  __builtin_amdgcn_global_load_lds((const __attribute__((address_space(1))) void*)(gp), \
                                   (__attribute__((address_space(3))) void*)(lp), 16, 0, 0)

// ---------------------------------------------------------------------------
// Kernel 1: hmid = relu(v @ w1 + b1), bf16, MFMA A-fragment order (verified):
//   frag = (r/16)*8 + k/32 ; lane = ((k/8)%4)*16 + r%16 ; elem = k%8
// ---------------------------------------------------------------------------
__global__ void prep_hmid(const float* __restrict__ v, const float* __restrict__ w1,
                          const float* __restrict__ b1, __hip_bfloat16* __restrict__ hmidp) {
  int r = blockIdx.x;      // 0..9215
  int t = threadIdx.x;     // 0..255 = hidden index k
  float v0 = v[r*3+0], v1 = v[r*3+1], v2 = v[r*3+2];
  float val = v0*w1[t] + v1*w1[HID+t] + v2*w1[2*HID+t] + b1[t];
  val = fmaxf(val, 0.0f);
  int dst = ((r>>4)*8 + (t>>5))*512 + ((t>>3)&3)*128 + (r&15)*8 + (t&7);
  hmidp[dst] = __float2bfloat16(val);
}

// ---------------------------------------------------------------------------
// Kernel 2: w2 -> bf16, B-fragment order grouped into 8KB slices (verified):
//   colchunk = col/128 (72), kb = k/32 (8), cg = (col%128)/16 (8),
//   lane = ((k/8)%4)*16 + col%16, elem = k%8
// ---------------------------------------------------------------------------
__global__ void prep_w2(const float* __restrict__ w2, __hip_bfloat16* __restrict__ w2p) {
  int idx = blockIdx.x*256 + threadIdx.x;   // 0 .. 256*9216-1
  int k   = idx / COLS;
  int col = idx % COLS;
  float val = w2[idx];                      // w2[k][col], row-major
  int colchunk = col >> 7;
  int cg   = (col >> 4) & 7;
  int lane = (((k>>3)&3)<<4) | (col & 15);
  int kb   = k >> 5;
  int i    = k & 7;
  int dst  = (((colchunk*8 + kb)*8 + cg)*64 + lane)*8 + i;
  w2p[dst] = __float2bfloat16(val);
}

// ---------------------------------------------------------------------------
// Kernel 3: fused GEMM + IN-REGISTER apply.
// Wave wv's GEMM cols (proven layout) are exactly f = ch*4+wv, oc 0..31.
// Apply runs directly on C-fragments: oacc2[n][mg][j] += (acc+bias)*pat.
// Chunk loop: ZERO barriers, ZERO wc, ZERO inline asm. Cross-wave f-sum done
// ONCE at the end (4-round LDS reduction, reusing the staging LDS).
// LDS dynamic 44,032B: Atile 16384 + patB 27648; redL (32KB) overlays after.
// ---------------------------------------------------------------------------
__launch_bounds__(256, 2)
__global__ void fused_main(const float* __restrict__ F_LR,
                           const __hip_bfloat16* __restrict__ hmidp,
                           const __hip_bfloat16* __restrict__ w2p,
                           const float* __restrict__ b2,
                           float* __restrict__ outp,
                           int G, int nch) {
  extern __shared__ __align__(16) char smem[];
  char*   AtileB = smem;                         // 16384B: [mg*8+kb][lane][8] bf16
  __bf16* patB   = (__bf16*)(smem + 16384);      // 27648B: [(c*3+ki)*18+wi][n]

  const int tid  = threadIdx.x;
  const int lane = tid & 63;
  const int wv   = tid >> 6;
  const int blk  = blockIdx.x;
  int rowtile, g;
  if (G == 2) {            // XCD-chunked decode (R10-proven, bijective)
    int xcd = blk & 7;
    int j   = blk >> 3;    // 0..71
    g       = xcd & 1;
    rowtile = (xcd >> 1)*72 + j;
  } else {
    rowtile = blk;
    g       = 0;
  }
  const int X  = rowtile / 3;
  const int Yh = rowtile - X*3;
  const int h  = X >> 1;
  const int w0 = Yh * 16;
  const int l15 = lane & 15;
  const int qt  = lane >> 4;

  const char* w2base = (const char*)w2p + (size_t)g*nch*65536;

  // ---- A tile -> LDS (16KB linear, R12-proven) ----
  {
    const char* hsrc = (const char*)hmidp + (size_t)rowtile*16384;
    #pragma unroll
    for (int j = 0; j < 4; ++j)
      GLOAD_LDS16(hsrc + j*4096 + wv*1024 + lane*16, AtileB + j*4096 + wv*1024);
  }

  // ---- stage patches (R11-proven layout): patB[(c*3+ki)*18+wi][n] ----
  {
    const int n = tid >> 5, c = tid & 31;
    const float* fsrc = F_LR + ((size_t)(n*CC + c)*HH)*WW;
    #pragma unroll
    for (int ki = 0; ki < 3; ++ki) {
      int hh = h - 1 + ki;
      bool hok = (unsigned)hh < (unsigned)HH;
      #pragma unroll
      for (int wi = 0; wi < 18; ++wi) {
        int ww = w0 - 1 + wi;
        float val = (hok && (unsigned)ww < (unsigned)WW) ? fsrc[hh*WW + ww] : 0.f;
        patB[((c*3 + ki)*18 + wi)*8 + n] = (__bf16)val;
      }
    }
  }
  __syncthreads();   // drains vmcnt (global_load_lds) + lgkm per HIP semantics

  f32x2 oacc2[8][2][4];                  // [n][mg][j], components = oc {l15, 16+l15}
  #pragma unroll
  for (int n = 0; n < 8; ++n)
    #pragma unroll
    for (int mg = 0; mg < 2; ++mg)
      #pragma unroll
      for (int j = 0; j < 4; ++j) oacc2[n][mg][j] = 0.f;

  for (int ch = 0; ch < nch; ++ch) {
    const int f   = (g*nch + ch)*4 + wv;
    const int c   = f / 9;
    const int rem = f - c*9;
    const int ki  = rem / 3;
    const int kj  = rem - ki*3;
    const float bias0 = b2[f*32 + l15];
    const float bias1 = b2[f*32 + 16 + l15];

    f32x4 acc00 = {0,0,0,0}, acc01 = {0,0,0,0}, acc10 = {0,0,0,0}, acc11 = {0,0,0,0};
    #pragma unroll
    for (int kb = 0; kb < 8; ++kb) {
      const char* bp = w2base + (size_t)(ch*8 + kb)*8192 + wv*2048 + (size_t)lane*16;
      bf16x8 b0 = *(const bf16x8*)(bp);
      bf16x8 b1 = *(const bf16x8*)(bp + 1024);
      bf16x8 a0 = *(const bf16x8*)(AtileB + kb*1024 + lane*16);
      bf16x8 a1 = *(const bf16x8*)(AtileB + 8192 + kb*1024 + lane*16);
      acc00 = __builtin_amdgcn_mfma_f32_16x16x32_bf16(a0, b0, acc00, 0,0,0);
      acc01 = __builtin_amdgcn_mfma_f32_16x16x32_bf16(a0, b1, acc01, 0,0,0);
      acc10 = __builtin_amdgcn_mfma_f32_16x16x32_bf16(a1, b0, acc10, 0,0,0);
      acc11 = __builtin_amdgcn_mfma_f32_16x16x32_bf16(a1, b1, acc11, 0,0,0);
    }

    // ---- pat fragments: rows r = mg*16+qt*4+j -> w_local = mg*8+2qt+(j>>1) ----
    const __bf16* prow = patB + (size_t)((c*3 + ki)*18)*8;
    const int w0i = 2*qt + kj;
    bf16x8 pw00 = *(const bf16x8*)(prow + (w0i    )*8);   // mg0, j=0,1
    bf16x8 pw01 = *(const bf16x8*)(prow + (w0i + 1)*8);   // mg0, j=2,3
    bf16x8 pw10 = *(const bf16x8*)(prow + (w0i + 8)*8);   // mg1, j=0,1
    bf16x8 pw11 = *(const bf16x8*)(prow + (w0i + 9)*8);   // mg1, j=2,3

    // ---- bias fold: accb[mg][j] = (accL[j]+bias0, accR[j]+bias1) ----
    f32x2 accb[2][4];
    #pragma unroll
    for (int j = 0; j < 4; ++j) {
      accb[0][j][0] = acc00[j] + bias0;  accb[0][j][1] = acc01[j] + bias1;
      accb[1][j][0] = acc10[j] + bias0;  accb[1][j][1] = acc11[j] + bias1;
    }

    // ---- in-register apply ----
    #pragma unroll
    for (int n = 0; n < 8; ++n) {
      float pv00 = (float)pw00[n];
      float pv01 = (float)pw01[n];
      float pv10 = (float)pw10[n];
      float pv11 = (float)pw11[n];
      oacc2[n][0][0] += accb[0][0] * pv00;
      oacc2[n][0][1] += accb[0][1] * pv00;
      oacc2[n][0][2] += accb[0][2] * pv01;
      oacc2[n][0][3] += accb[0][3] * pv01;
      oacc2[n][1][0] += accb[1][0] * pv10;
      oacc2[n][1][1] += accb[1][1] * pv10;
      oacc2[n][1][2] += accb[1][2] * pv11;
      oacc2[n][1][3] += accb[1][3] * pv11;
    }
  }

  // ---- final cross-wave f-reduction (4 rounds, overlays staging LDS) ----
  float* redL = (float*)smem;                    // 32,768B used
  float* OP = outp + (size_t)g*OUTSZ;
  #pragma unroll
  for (int np = 0; np < 2; ++np) {
    #pragma unroll
    for (int mg = 0; mg < 2; ++mg) {
      __syncthreads();                           // previous round reads done
      #pragma unroll
      for (int q = 0; q < 4; ++q) {
        #pragma unroll
        for (int comp = 0; comp < 2; ++comp) {
          f32x4 vv;
          vv[0] = oacc2[np*4+q][mg][0][comp];
          vv[1] = oacc2[np*4+q][mg][1][comp];
          vv[2] = oacc2[np*4+q][mg][2][comp];
          vv[3] = oacc2[np*4+q][mg][3][comp];
          *(f32x4*)&redL[(((wv*4 + q)*2 + comp)*64 + lane)*4] = vv;
        }
      }
      __syncthreads();                           // writes visible
      const int n = np*4 + wv;                   // reader wave wv owns n
      #pragma unroll
      for (int comp = 0; comp < 2; ++comp) {
        f32x4 s = *(const f32x4*)&redL[(((0*4 + wv)*2 + comp)*64 + lane)*4];
        #pragma unroll
        for (int w = 1; w < 4; ++w)
          s += *(const f32x4*)&redL[(((w*4 + wv)*2 + comp)*64 + lane)*4];
        const int ocx = comp*16 + l15;
        float* dst = OP + (((size_t)(n*OCC + ocx)*XUP + X)*YUP + Yh*32 + mg*16 + qt*4);
        *(f32x4*)dst = s;
      }
    }
  }
}

// ---------------------------------------------------------------------------
// Kernel 4 (G=2 only): out = P0 + P1 (deterministic)
// ---------------------------------------------------------------------------
__global__ void reduce2(const float* __restrict__ P, float* __restrict__ out) {
  int i = blockIdx.x*256 + threadIdx.x;
  if (i < OUTSZ/4) {
    f32x4 a = ((const f32x4*)P)[i];
    f32x4 b = ((const f32x4*)(P + OUTSZ))[i];
    ((f32x4*)out)[i] = a + b;
  }
}

// ---------------------------------------------------------------------------
extern "C" void kernel_launch(void* const* d_in, const int* in_sizes, int n_in,
                              void* d_out, int out_size, void* d_ws, size_t ws_size,
                              hipStream_t stream) {
  const float* F_LR = (const float*)d_in[0];
  const float* v    = (const float*)d_in[1];
  const float* w1   = (const float*)d_in[2];
  const float* b1   = (const float*)d_in[3];
  const float* w2   = (const float*)d_in[4];
  const float* b2   = (const float*)d_in[5];
  float* out = (float*)d_out;

  const size_t prepBytes = (size_t)RTOT*HID*2;          // 4,718,592 each
  const size_t need2 = 2*prepBytes + 2ull*OUTSZ*4;      // 28,311,552
  const int G   = (ws_size >= need2) ? 2 : 1;
  const int nch = 72 / G;

  __hip_bfloat16* hmidp = (__hip_bfloat16*)d_ws;
  __hip_bfloat16* w2p   = (__hip_bfloat16*)((char*)d_ws + prepBytes);
  float* P = (float*)((char*)d_ws + 2*prepBytes);
  float* target = (G == 2) ? P : out;

  const size_t shmem = 16384 + 27648;                   // 44,032 B

  hipLaunchKernelGGL(prep_hmid, dim3(RTOT), dim3(HID), 0, stream, v, w1, b1, hmidp);
  hipLaunchKernelGGL(prep_w2,   dim3((HID*COLS)/256), dim3(256), 0, stream, w2, w2p);
  hipLaunchKernelGGL(fused_main, dim3(288*G), dim3(256), shmem, stream,
                     F_LR, hmidp, w2p, b2, target, G, nch);
  if (G == 2)
    hipLaunchKernelGGL(reduce2, dim3(OUTSZ/4/256), dim3(256), 0, stream, P, out);
}